// Round 14
// baseline (141.544 us; speedup 1.0000x reference)
//
#include <hip/hip_runtime.h>

typedef __bf16 bf16x8 __attribute__((ext_vector_type(8)));
typedef __bf16 bf16x4 __attribute__((ext_vector_type(4)));
typedef float  f32x4  __attribute__((ext_vector_type(4)));
typedef float  f32x16 __attribute__((ext_vector_type(16)));
typedef unsigned u32x2 __attribute__((ext_vector_type(2)));

#define DEVINL __device__ __forceinline__

DEVINL void gload_lds16(const void* g, void* l) {
  __builtin_amdgcn_global_load_lds((const __attribute__((address_space(1))) void*)g,
                                   (__attribute__((address_space(3))) void*)l, 16, 0, 0);
}

// exchange lane halves: returns {x from lanes0-31 view, x from lanes32-63 view}
DEVINL float2 swap32(float x) {
  u32x2 r = __builtin_amdgcn_permlane32_swap(__float_as_uint(x), __float_as_uint(x), false, false);
  return make_float2(__uint_as_float(r.x), __uint_as_float(r.y));
}

DEVINL float fast_rcp(float x) {
#if __has_builtin(__builtin_amdgcn_rcpf)
  return __builtin_amdgcn_rcpf(x);
#else
  return 1.0f / x;
#endif
}

// ---------------- prep: RMSNorm(img)+RMSNorm(cnd) + weight cast, one launch ----------------
__global__ __launch_bounds__(256) void prep_kernel(
    const float* __restrict__ XA, const float* __restrict__ WA, __bf16* __restrict__ YA,
    const float* __restrict__ XB, const float* __restrict__ WB, __bf16* __restrict__ YB,
    const float* __restrict__ wq, const float* __restrict__ wk,
    const float* __restrict__ wv, const float* __restrict__ wo,
    __bf16* __restrict__ oq, __bf16* __restrict__ ok,
    __bf16* __restrict__ ov, __bf16* __restrict__ oo) {
  int rb = blockIdx.x, tid = threadIdx.x;
  if (rb < 10240) {
    const float* X; const float* W; __bf16* Y; int row;
    if (rb < 8192) { X = XA; W = WA; Y = YA; row = rb; }
    else { X = XB; W = WB; Y = YB; row = rb - 8192; }
    const float4* xr = (const float4*)(X + (size_t)row * 1024);
    float4 v = xr[tid];
    float ss = v.x * v.x + v.y * v.y + v.z * v.z + v.w * v.w;
#pragma unroll
    for (int m = 1; m < 64; m <<= 1) ss += __shfl_xor(ss, m);
    __shared__ float part[4];
    if ((tid & 63) == 0) part[tid >> 6] = ss;
    __syncthreads();
    float tot = part[0] + part[1] + part[2] + part[3];
    float rn = rsqrtf(tot * (1.0f / 1024.0f) + 1e-6f);
    float4 wv4 = ((const float4*)W)[tid];
    bf16x4 y;
    y[0] = (__bf16)(v.x * rn * wv4.x);
    y[1] = (__bf16)(v.y * rn * wv4.y);
    y[2] = (__bf16)(v.z * rn * wv4.z);
    y[3] = (__bf16)(v.w * rn * wv4.w);
    *(bf16x4*)(Y + (size_t)row * 1024 + tid * 4) = y;
  } else {
    int gid = (rb - 10240) * 256 + tid;
    int which = gid >> 17;
    size_t off = (size_t)(gid & 131071) * 8;
    const float* s = (which == 0) ? wq : (which == 1) ? wk : (which == 2) ? wv : wo;
    __bf16* o = (which == 0) ? oq : (which == 1) ? ok : (which == 2) ? ov : oo;
    float4 v0 = *(const float4*)(s + off), v1 = *(const float4*)(s + off + 4);
    bf16x8 y;
    y[0] = (__bf16)v0.x; y[1] = (__bf16)v0.y; y[2] = (__bf16)v0.z; y[3] = (__bf16)v0.w;
    y[4] = (__bf16)v1.x; y[5] = (__bf16)v1.y; y[6] = (__bf16)v1.z; y[7] = (__bf16)v1.w;
    *(bf16x8*)(o + off) = y;
  }
}

// ---------------- GEMM core: 128x128 tile, 3-buffer, 2-ahead, ONE barrier + vmcnt(4)/step ----
template <typename EPIF>
DEVINL void gemm_core(const __bf16* __restrict__ A, const __bf16* __restrict__ Bw,
                      int m0, int n0, char* AsB, char* BsB, EPIF epi) {
  int tid = threadIdx.x, lane = tid & 63, w = tid >> 6, wr = w >> 1, wc = w & 1;
  f32x4 z4 = {0.f, 0.f, 0.f, 0.f};
  f32x4 acc[4][4];
#pragma unroll
  for (int i = 0; i < 4; i++)
#pragma unroll
    for (int j = 0; j < 4; j++) acc[i][j] = z4;

  auto STAGE = [&](int k0, int bsel) {
#pragma unroll
    for (int i = 0; i < 2; i++) {
      int chunk = i * 256 + tid;
      int row = chunk >> 2, cc = chunk & 3;
      gload_lds16(A + (size_t)(m0 + row) * 1024 + k0 + cc * 8,
                  AsB + bsel * 8192 + i * 4096 + w * 1024);
      gload_lds16(Bw + (size_t)(n0 + row) * 1024 + k0 + cc * 8,
                  BsB + bsel * 8192 + i * 4096 + w * 1024);
    }
  };

  // 2-ahead prologue
  STAGE(0, 0);
  STAGE(32, 1);
  asm volatile("s_waitcnt vmcnt(4)" ::: "memory");   // step-0 data resident
  __builtin_amdgcn_s_barrier();
  asm volatile("" ::: "memory");

  for (int it = 0; it < 32; ++it) {
    int bsel = it % 3;
    const char* As = AsB + bsel * 8192;
    const char* Bs = BsB + bsel * 8192;
    bf16x8 af[4], bfr[4];
#pragma unroll
    for (int m = 0; m < 4; m++) {
      int r = wr * 64 + m * 16 + (lane & 15);
      af[m] = *(const bf16x8*)(As + r * 64 + ((lane >> 4) << 4));
    }
#pragma unroll
    for (int n = 0; n < 4; n++) {
      int r = wc * 64 + n * 16 + (lane & 15);
      bfr[n] = *(const bf16x8*)(Bs + r * 64 + ((lane >> 4) << 4));
    }
    if (it + 2 < 32) STAGE((it + 2) * 32, (it + 2) % 3);
    __builtin_amdgcn_s_setprio(1);
#pragma unroll
    for (int m = 0; m < 4; m++)
#pragma unroll
      for (int n = 0; n < 4; n++)
        acc[m][n] = __builtin_amdgcn_mfma_f32_16x16x32_bf16(af[m], bfr[n], acc[m][n], 0, 0, 0);
    __builtin_amdgcn_s_setprio(0);
    // counted wait: next step's 4 loads complete, next-next's stay in flight
    if (it + 2 < 32) {
      asm volatile("s_waitcnt vmcnt(4)" ::: "memory");
    } else if (it + 1 < 32) {
      asm volatile("s_waitcnt vmcnt(0)" ::: "memory");
    }
    __builtin_amdgcn_s_barrier();
    asm volatile("" ::: "memory");
  }
  epi(acc, lane, wr, wc);
}

// ---------------- merged Q + KV projection GEMM (768 blocks, all bf16-out) ----------------
__global__ __launch_bounds__(256) void qkv_gemm_kernel(
    const __bf16* __restrict__ qn, const __bf16* __restrict__ kvn,
    const __bf16* __restrict__ wq, const __bf16* __restrict__ wkv,
    const float* __restrict__ qb, const float* __restrict__ kb, const float* __restrict__ vb,
    __bf16* __restrict__ Qt, __bf16* __restrict__ Kt, __bf16* __restrict__ Vt0) {
  __shared__ __attribute__((aligned(16))) char AsB[3 * 8192];
  __shared__ __attribute__((aligned(16))) char BsB[3 * 8192];
  int id = blockIdx.x;
  const __bf16 *A, *Bw; const float* bias; __bf16* Cout;
  int m0, n0, nloc;
  if (id < 512) {
    A = qn; Bw = wq; m0 = (id & 63) * 128; n0 = (id >> 6) * 128; nloc = n0;
    bias = qb; Cout = Qt;
  } else {
    int i2 = id - 512;
    A = kvn; Bw = wkv; m0 = (i2 & 15) * 128; n0 = (i2 >> 4) * 128;
    if (n0 < 1024) { bias = kb; Cout = Kt; nloc = n0; }
    else { bias = vb; Cout = Vt0; nloc = n0 - 1024; }
  }
  gemm_core(A, Bw, m0, n0, AsB, BsB,
            [&](f32x4 (&acc)[4][4], int lane, int wr, int wc) {
#pragma unroll
              for (int m = 0; m < 4; m++)
#pragma unroll
                for (int n = 0; n < 4; n++) {
                  int col = nloc + wc * 64 + n * 16 + (lane & 15);
                  float bv = bias[col];
#pragma unroll
                  for (int r = 0; r < 4; r++) {
                    int row = m0 + wr * 64 + m * 16 + ((lane >> 4) << 2) + r;
                    Cout[((size_t)row << 10) + col] = (__bf16)(acc[m][n][r] + bv);
                  }
                }
            });
}

// ---------------- O-projection GEMM with residual epilogue (512 blocks) ----------------
__global__ __launch_bounds__(256) void gemm_o_kernel(
    const __bf16* __restrict__ A, const __bf16* __restrict__ Bw,
    const float* __restrict__ bias, float* __restrict__ Cout,
    const float* __restrict__ resid, const float* __restrict__ alphap) {
  __shared__ __attribute__((aligned(16))) char AsB[3 * 8192];
  __shared__ __attribute__((aligned(16))) char BsB[3 * 8192];
  int m0 = blockIdx.x * 128, n0 = blockIdx.y * 128;
  float aval = alphap[0];
  gemm_core(A, Bw, m0, n0, AsB, BsB,
            [&](f32x4 (&acc)[4][4], int lane, int wr, int wc) {
#pragma unroll
              for (int m = 0; m < 4; m++)
#pragma unroll
                for (int n = 0; n < 4; n++) {
                  int col = n0 + wc * 64 + n * 16 + (lane & 15);
                  float bv = bias[col];
#pragma unroll
                  for (int r = 0; r < 4; r++) {
                    int row = m0 + wr * 64 + m * 16 + ((lane >> 4) << 2) + r;
                    size_t idx = ((size_t)row << 10) + col;
                    Cout[idx] = resid[idx] + aval * (acc[m][n][r] + bv);
                  }
                }
            });
}

// ---------------- kprep: K head-RMSNorm+RoPE ∪ V transpose, one launch ----------------
__global__ __launch_bounds__(256) void kprep_kernel(
    const __bf16* __restrict__ Kt, const float* __restrict__ KHW,
    const float* __restrict__ CCOS, const float* __restrict__ CSIN,
    __bf16* __restrict__ Kr,
    const __bf16* __restrict__ V, __bf16* __restrict__ Vt) {
  int rb = blockIdx.x, tid = threadIdx.x;
  if (rb < 1024) {
    int inst = rb * 32 + (tid >> 3);
    int sub = tid & 7;
    int token = inst >> 4, h = inst & 15;
    int b = token >> 10, pos = token & 1023;
    const __bf16* xp = Kt + ((size_t)token << 10) + h * 64 + sub * 8;
    bf16x8 xv = *(const bf16x8*)xp;
    float xf[8];
#pragma unroll
    for (int i = 0; i < 8; i++) xf[i] = (float)xv[i];
    float ss = 0.f;
#pragma unroll
    for (int i = 0; i < 8; i++) ss += xf[i] * xf[i];
    ss += __shfl_xor(ss, 1);
    ss += __shfl_xor(ss, 2);
    ss += __shfl_xor(ss, 4);
    float rn = rsqrtf(ss * (1.0f / 64.0f) + 1e-6f);
    const float* hwp = KHW + sub * 8;
    const float* cp = CCOS + ((size_t)pos << 6) + sub * 8;
    const float* sp = CSIN + ((size_t)pos << 6) + sub * 8;
    float xn[8], o[8];
#pragma unroll
    for (int i = 0; i < 8; i++) xn[i] = xf[i] * rn * hwp[i];
#pragma unroll
    for (int i = 0; i < 8; i += 2) {
      o[i] = xn[i] * cp[i] - xn[i + 1] * sp[i];
      o[i + 1] = xn[i + 1] * cp[i + 1] + xn[i] * sp[i + 1];
    }
    bf16x8 yv;
#pragma unroll
    for (int i = 0; i < 8; i++) yv[i] = (__bf16)o[i];
    *(bf16x8*)(Kr + (((size_t)((b << 4) + h) << 10) + pos) * 64 + sub * 8) = yv;
  } else {
    int bx = rb - 1024;
    int bh = bx >> 4;
    int j0 = (bx & 15) * 64;
    int b = bh >> 4, h = bh & 15;
#pragma unroll
    for (int it = 0; it < 2; ++it) {
      int c = it * 256 + tid;
      int jl = c >> 3, d0 = (c & 7) * 8;
      bf16x8 v = *(const bf16x8*)(V + (size_t)(b * 1024 + j0 + jl) * 1024 + h * 64 + d0);
#pragma unroll
      for (int i = 0; i < 8; i++)
        Vt[((size_t)bh * 64 + d0 + i) * 1024 + j0 + jl] = v[i];
    }
  }
}

// ---------------- flash attention: 128q/block (32q/wave), 3-buffer counted-vmcnt ----------
// Qt: (B*4096,1024) bf16 ; Kr: (B,16,1024,64) ; Vtr: (B,16,64,1024) ; AO: (B*4096,1024).
// 4 waves/block, each wave ONE 32-q subtile (lane&31=q) -> grid 1024, 3 blocks/CU
// (LDS-capped), ~12 waves/CU vs r13's 2-block/CU grid cap. Fragment-linear LDS (8 slots
// x 1KB per K/V tile), zero conflicts. 3 buffers, 2-tile-ahead, ONE raw s_barrier +
// s_waitcnt vmcnt(4) per tile. Softmax: bit-trick bf16 exp2 (bits = s*128 + MAGIC) +
// ones-MFMA row-sum (denominator lane-local). XCD swizzle: 4 heads/XCD.
__global__ __launch_bounds__(256) void attn_kernel(
    const __bf16* __restrict__ Qt, const float* __restrict__ QHW,
    const float* __restrict__ QCOS, const float* __restrict__ QSIN,
    const __bf16* __restrict__ Kr, const __bf16* __restrict__ Vtr,
    __bf16* __restrict__ AO) {
  int tid = threadIdx.x, lane = tid & 63, w = tid >> 6;
  int lq = lane & 31, hi = lane >> 5;
  // XCD swizzle (1024 blocks, 8 XCDs, 128 blocks/XCD -> 4 heads per XCD; 1024%8==0 bijective)
  int wgid = blockIdx.x;
  int nid = (wgid & 7) * 128 + (wgid >> 3);
  int q0 = (nid & 31) * 128;
  int bh = nid >> 5, b = bh >> 4, h = bh & 15;
  const float QSC = 0.125f * 1.44269504088896340736f;  // 1/sqrt(64) * log2(e)
  const float MAGIC = 16250.5f;                        // (127 - 0.043) * 128, centered error

  __shared__ __attribute__((aligned(16))) __bf16 Ks[3][4096];
  __shared__ __attribute__((aligned(16))) __bf16 Vs[3][4096];

  const __bf16* Kbh = Kr + ((size_t)bh << 16);
  const __bf16* Vbh = Vtr + ((size_t)bh << 16);

  auto STAGE = [&](int T, int BSEL) {
#pragma unroll
    for (int i = 0; i < 2; i++) {
      int s = 2 * w + i;
      int kt = s >> 2, ds2 = s & 3;
      gload_lds16(Kbh + (size_t)(T * 64 + kt * 32 + lq) * 64 + ds2 * 16 + hi * 8,
                  (char*)Ks[BSEL] + s * 1024);
      int f = s >> 1, dh = s & 1;
      gload_lds16(Vbh + (size_t)(dh * 32 + lq) * 1024 + T * 64 + f * 16 + hi * 8,
                  (char*)Vs[BSEL] + s * 1024);
    }
  };

  STAGE(0, 0);
  STAGE(1, 1);

  // ---- fused Q head-RMSNorm + RoPE + scale (wave's 32 q-rows; overlaps staging)
  bf16x8 qf[4];
  {
    int pos = q0 + w * 32 + lq;
    const __bf16* qp = Qt + ((size_t)(b * 4096 + pos) << 10) + h * 64 + hi * 8;
    float xf[4][8];
    float ss = 0.f;
#pragma unroll
    for (int ds = 0; ds < 4; ds++) {
      bf16x8 xv = *(const bf16x8*)(qp + ds * 16);
#pragma unroll
      for (int j = 0; j < 8; j++) { float f = (float)xv[j]; xf[ds][j] = f; ss += f * f; }
    }
    float2 sw = swap32(ss);
    float rn = rsqrtf((sw.x + sw.y) * (1.0f / 64.0f) + 1e-6f);
#pragma unroll
    for (int ds = 0; ds < 4; ds++) {
      int d0 = ds * 16 + hi * 8;
      const float* wp = QHW + d0;
      const float* cp = QCOS + ((size_t)pos << 6) + d0;
      const float* sp = QSIN + ((size_t)pos << 6) + d0;
      float4 wa = *(const float4*)wp, wb = *(const float4*)(wp + 4);
      float4 ca = *(const float4*)cp, cb = *(const float4*)(cp + 4);
      float4 sa = *(const float4*)sp, sb = *(const float4*)(sp + 4);
      float wv[8] = {wa.x, wa.y, wa.z, wa.w, wb.x, wb.y, wb.z, wb.w};
      float cv[8] = {ca.x, ca.y, ca.z, ca.w, cb.x, cb.y, cb.z, cb.w};
      float sv[8] = {sa.x, sa.y, sa.z, sa.w, sb.x, sb.y, sb.z, sb.w};
      float xn[8];
#pragma unroll
      for (int j = 0; j < 8; j++) xn[j] = xf[ds][j] * rn * wv[j];
      bf16x8 q8;
#pragma unroll
      for (int j = 0; j < 8; j += 2) {
        q8[j]     = (__bf16)((xn[j] * cv[j] - xn[j + 1] * sv[j]) * QSC);
        q8[j + 1] = (__bf16)((xn[j + 1] * cv[j + 1] + xn[j] * sv[j + 1]) * QSC);
      }
      qf[ds] = q8;
    }
  }

  f32x16 Z16;
#pragma unroll
  for (int r = 0; r < 16; r++) Z16[r] = 0.f;
  f32x16 accO[2], accR;
  accO[0] = Z16; accO[1] = Z16; accR = Z16;
  bf16x8 ones8;
#pragma unroll
  for (int i = 0; i < 8; i++) ones8[i] = (__bf16)1.0f;

  // tile 0 resident (tile 1's loads may stay in flight)
  asm volatile("s_waitcnt vmcnt(4)" ::: "memory");
  __builtin_amdgcn_s_barrier();
  asm volatile("" ::: "memory");

  for (int t = 0; t < 16; t++) {
    int cur = t % 3;
    const char* kbase = (const char*)Ks[cur];
    const char* vbase = (const char*)Vs[cur];
    int loff = lane * 16;

    bf16x8 kf[8], vf[8];
#pragma unroll
    for (int s = 0; s < 8; s++) kf[s] = *(const bf16x8*)(kbase + s * 1024 + loff);
#pragma unroll
    for (int s = 0; s < 8; s++) vf[s] = *(const bf16x8*)(vbase + s * 1024 + loff);

    if (t + 2 < 16) STAGE(t + 2, (t + 2) % 3);

    f32x16 accS[2];
    __builtin_amdgcn_s_setprio(1);
#pragma unroll
    for (int kt = 0; kt < 2; kt++) {
      accS[kt] = __builtin_amdgcn_mfma_f32_32x32x16_bf16(kf[kt * 4], qf[0], Z16, 0, 0, 0);
#pragma unroll
      for (int ds = 1; ds < 4; ds++)
        accS[kt] = __builtin_amdgcn_mfma_f32_32x32x16_bf16(kf[kt * 4 + ds], qf[ds], accS[kt], 0, 0, 0);
    }
    __builtin_amdgcn_s_setprio(0);

    // P = approx exp2(S) as bf16 bits: bits16 = (u16)(s*128 + MAGIC)
    unsigned pa[4][4];
#pragma unroll
    for (int kt = 0; kt < 2; kt++)
#pragma unroll
      for (int s2 = 0; s2 < 2; s2++) {
        int f = kt * 2 + s2, rb = s2 * 8;
        unsigned q[4];
#pragma unroll
        for (int i = 0; i < 4; i++) {
          float t0 = fmaf(accS[kt][rb + 2 * i], 128.f, MAGIC);
          float t1 = fmaf(accS[kt][rb + 2 * i + 1], 128.f, MAGIC);
          q[i] = ((unsigned)t1 << 16) | (unsigned)t0;
        }
        u32x2 r02 = __builtin_amdgcn_permlane32_swap(q[0], q[2], false, false);
        u32x2 r13 = __builtin_amdgcn_permlane32_swap(q[1], q[3], false, false);
        pa[f][0] = r02.x; pa[f][1] = r13.x; pa[f][2] = r02.y; pa[f][3] = r13.y;
      }

    __builtin_amdgcn_s_setprio(1);
#pragma unroll
    for (int f = 0; f < 4; f++) {
      union { unsigned u[4]; bf16x8 v; } pf;
      pf.u[0] = pa[f][0]; pf.u[1] = pa[f][1]; pf.u[2] = pa[f][2]; pf.u[3] = pa[f][3];
      accO[0] = __builtin_amdgcn_mfma_f32_32x32x16_bf16(pf.v, vf[f * 2 + 0], accO[0], 0, 0, 0);
      accO[1] = __builtin_amdgcn_mfma_f32_32x32x16_bf16(pf.v, vf[f * 2 + 1], accO[1], 0, 0, 0);
      accR    = __builtin_amdgcn_mfma_f32_32x32x16_bf16(pf.v, ones8, accR, 0, 0, 0);
    }
    __builtin_amdgcn_s_setprio(0);

    // counted wait: tile t+1's loads complete; t+2's stay in flight
    if (t + 2 < 16) {
      asm volatile("s_waitcnt vmcnt(4)" ::: "memory");
    } else if (t + 1 < 16) {
      asm volatile("s_waitcnt vmcnt(0)" ::: "memory");
    }
    __builtin_amdgcn_s_barrier();
    asm volatile("" ::: "memory");
  }

  // epilogue: denominator lane-local (accR rows == accO rows); no cross-lane ops
  __bf16* aobase = AO + (((size_t)b * 4096) << 10) + h * 64;
#pragma unroll
  for (int r = 0; r < 16; r++) {
    float rv = fast_rcp(accR[r]);
    int cr = (r & 3) + ((r >> 2) << 3) + (hi << 2);
    size_t rowoff = ((size_t)(q0 + w * 32 + cr) << 10);
#pragma unroll
    for (int dh = 0; dh < 2; dh++)
      aobase[rowoff + dh * 32 + lq] = (__bf16)(accO[dh][r] * rv);
  }
}

extern "C" void kernel_launch(void* const* d_in, const int* in_sizes, int n_in,
                              void* d_out, int out_size, void* d_ws, size_t ws_size,
                              hipStream_t stream) {
  const float* img  = (const float*)d_in[0];
  const float* cnd  = (const float*)d_in[1];
  const float* qnw  = (const float*)d_in[2];
  const float* kvnw = (const float*)d_in[3];
  const float* qhw  = (const float*)d_in[4];
  const float* khw  = (const float*)d_in[5];
  const float* qw   = (const float*)d_in[6];
  const float* qb   = (const float*)d_in[7];
  const float* kw   = (const float*)d_in[8];
  const float* kb   = (const float*)d_in[9];
  const float* vw   = (const float*)d_in[10];
  const float* vb   = (const float*)d_in[11];
  const float* ow   = (const float*)d_in[12];
  const float* ob   = (const float*)d_in[13];
  const float* alpha= (const float*)d_in[14];
  const float* icos = (const float*)d_in[15];
  const float* isin = (const float*)d_in[16];
  const float* ccos = (const float*)d_in[17];
  const float* csin = (const float*)d_in[18];
  float* out = (float*)d_out;

  __bf16* p = (__bf16*)d_ws;
  __bf16* wqb = p; p += 1048576;
  __bf16* wkb = p; p += 1048576;   // wkb..wvb contiguous = (2048,1024) KV weight
  __bf16* wvb = p; p += 1048576;
  __bf16* wob = p; p += 1048576;
  __bf16* qn  = p; p += 8388608;   // (8192,1024); reused as AO after Q-GEMM consumes it
  __bf16* kvn = p; p += 2097152;
  __bf16* Qt  = p; p += 8388608;
  __bf16* Kt  = p; p += 2097152;
  __bf16* Vt0 = p; p += 2097152;
  __bf16* Kr  = p; p += 2097152;
  __bf16* Vtr = p; p += 2097152;
  __bf16* AO  = qn;  // qn dead after Q-GEMM

  prep_kernel<<<12288, 256, 0, stream>>>(img, qnw, qn, cnd, kvnw, kvn,
                                         qw, kw, vw, ow, wqb, wkb, wvb, wob);

  qkv_gemm_kernel<<<768, 256, 0, stream>>>(qn, kvn, wqb, wkb, qb, kb, vb, Qt, Kt, Vt0);

  kprep_kernel<<<1536, 256, 0, stream>>>(Kt, khw, ccos, csin, Kr, Vt0, Vtr);

  attn_kernel<<<1024, 256, 0, stream>>>(Qt, qhw, icos, isin, Kr, Vtr, AO);

  gemm_o_kernel<<<dim3(64, 8), 256, 0, stream>>>(AO, wob, ob, out, img, alpha);
}

// Round 15
// 132.490 us; speedup vs baseline: 1.0683x; 1.0683x over previous
//
#include <hip/hip_runtime.h>

typedef __bf16 bf16x8 __attribute__((ext_vector_type(8)));
typedef __bf16 bf16x4 __attribute__((ext_vector_type(4)));
typedef float  f32x4  __attribute__((ext_vector_type(4)));
typedef float  f32x16 __attribute__((ext_vector_type(16)));
typedef unsigned u32x2 __attribute__((ext_vector_type(2)));

#define DEVINL __device__ __forceinline__

DEVINL void gload_lds16(const void* g, void* l) {
  __builtin_amdgcn_global_load_lds((const __attribute__((address_space(1))) void*)g,
                                   (__attribute__((address_space(3))) void*)l, 16, 0, 0);
}

// exchange lane halves: returns {x from lanes0-31 view, x from lanes32-63 view}
DEVINL float2 swap32(float x) {
  u32x2 r = __builtin_amdgcn_permlane32_swap(__float_as_uint(x), __float_as_uint(x), false, false);
  return make_float2(__uint_as_float(r.x), __uint_as_float(r.y));
}

DEVINL float fast_rcp(float x) {
#if __has_builtin(__builtin_amdgcn_rcpf)
  return __builtin_amdgcn_rcpf(x);
#else
  return 1.0f / x;
#endif
}

// ---------------- prep: RMSNorm(img)+RMSNorm(cnd) + weight cast, one launch ----------------
__global__ __launch_bounds__(256) void prep_kernel(
    const float* __restrict__ XA, const float* __restrict__ WA, __bf16* __restrict__ YA,
    const float* __restrict__ XB, const float* __restrict__ WB, __bf16* __restrict__ YB,
    const float* __restrict__ wq, const float* __restrict__ wk,
    const float* __restrict__ wv, const float* __restrict__ wo,
    __bf16* __restrict__ oq, __bf16* __restrict__ ok,
    __bf16* __restrict__ ov, __bf16* __restrict__ oo) {
  int rb = blockIdx.x, tid = threadIdx.x;
  if (rb < 10240) {
    const float* X; const float* W; __bf16* Y; int row;
    if (rb < 8192) { X = XA; W = WA; Y = YA; row = rb; }
    else { X = XB; W = WB; Y = YB; row = rb - 8192; }
    const float4* xr = (const float4*)(X + (size_t)row * 1024);
    float4 v = xr[tid];
    float ss = v.x * v.x + v.y * v.y + v.z * v.z + v.w * v.w;
#pragma unroll
    for (int m = 1; m < 64; m <<= 1) ss += __shfl_xor(ss, m);
    __shared__ float part[4];
    if ((tid & 63) == 0) part[tid >> 6] = ss;
    __syncthreads();
    float tot = part[0] + part[1] + part[2] + part[3];
    float rn = rsqrtf(tot * (1.0f / 1024.0f) + 1e-6f);
    float4 wv4 = ((const float4*)W)[tid];
    bf16x4 y;
    y[0] = (__bf16)(v.x * rn * wv4.x);
    y[1] = (__bf16)(v.y * rn * wv4.y);
    y[2] = (__bf16)(v.z * rn * wv4.z);
    y[3] = (__bf16)(v.w * rn * wv4.w);
    *(bf16x4*)(Y + (size_t)row * 1024 + tid * 4) = y;
  } else {
    int gid = (rb - 10240) * 256 + tid;
    int which = gid >> 17;
    size_t off = (size_t)(gid & 131071) * 8;
    const float* s = (which == 0) ? wq : (which == 1) ? wk : (which == 2) ? wv : wo;
    __bf16* o = (which == 0) ? oq : (which == 1) ? ok : (which == 2) ? ov : oo;
    float4 v0 = *(const float4*)(s + off), v1 = *(const float4*)(s + off + 4);
    bf16x8 y;
    y[0] = (__bf16)v0.x; y[1] = (__bf16)v0.y; y[2] = (__bf16)v0.z; y[3] = (__bf16)v0.w;
    y[4] = (__bf16)v1.x; y[5] = (__bf16)v1.y; y[6] = (__bf16)v1.z; y[7] = (__bf16)v1.w;
    *(bf16x8*)(o + off) = y;
  }
}

// ---------------- GEMM core: 128x128 tile, 3-buffer, 2-ahead, ONE barrier + vmcnt(4)/step ----
template <typename EPIF>
DEVINL void gemm_core(const __bf16* __restrict__ A, const __bf16* __restrict__ Bw,
                      int m0, int n0, char* AsB, char* BsB, EPIF epi) {
  int tid = threadIdx.x, lane = tid & 63, w = tid >> 6, wr = w >> 1, wc = w & 1;
  f32x4 z4 = {0.f, 0.f, 0.f, 0.f};
  f32x4 acc[4][4];
#pragma unroll
  for (int i = 0; i < 4; i++)
#pragma unroll
    for (int j = 0; j < 4; j++) acc[i][j] = z4;

  auto STAGE = [&](int k0, int bsel) {
#pragma unroll
    for (int i = 0; i < 2; i++) {
      int chunk = i * 256 + tid;
      int row = chunk >> 2, cc = chunk & 3;
      gload_lds16(A + (size_t)(m0 + row) * 1024 + k0 + cc * 8,
                  AsB + bsel * 8192 + i * 4096 + w * 1024);
      gload_lds16(Bw + (size_t)(n0 + row) * 1024 + k0 + cc * 8,
                  BsB + bsel * 8192 + i * 4096 + w * 1024);
    }
  };

  // 2-ahead prologue
  STAGE(0, 0);
  STAGE(32, 1);
  asm volatile("s_waitcnt vmcnt(4)" ::: "memory");   // step-0 data resident
  __builtin_amdgcn_s_barrier();
  asm volatile("" ::: "memory");

  for (int it = 0; it < 32; ++it) {
    int bsel = it % 3;
    const char* As = AsB + bsel * 8192;
    const char* Bs = BsB + bsel * 8192;
    bf16x8 af[4], bfr[4];
#pragma unroll
    for (int m = 0; m < 4; m++) {
      int r = wr * 64 + m * 16 + (lane & 15);
      af[m] = *(const bf16x8*)(As + r * 64 + ((lane >> 4) << 4));
    }
#pragma unroll
    for (int n = 0; n < 4; n++) {
      int r = wc * 64 + n * 16 + (lane & 15);
      bfr[n] = *(const bf16x8*)(Bs + r * 64 + ((lane >> 4) << 4));
    }
    if (it + 2 < 32) STAGE((it + 2) * 32, (it + 2) % 3);
    __builtin_amdgcn_s_setprio(1);
#pragma unroll
    for (int m = 0; m < 4; m++)
#pragma unroll
      for (int n = 0; n < 4; n++)
        acc[m][n] = __builtin_amdgcn_mfma_f32_16x16x32_bf16(af[m], bfr[n], acc[m][n], 0, 0, 0);
    __builtin_amdgcn_s_setprio(0);
    // counted wait: next step's 4 loads complete, next-next's stay in flight
    if (it + 2 < 32) {
      asm volatile("s_waitcnt vmcnt(4)" ::: "memory");
    } else if (it + 1 < 32) {
      asm volatile("s_waitcnt vmcnt(0)" ::: "memory");
    }
    __builtin_amdgcn_s_barrier();
    asm volatile("" ::: "memory");
  }
  epi(acc, lane, wr, wc);
}

// ---------------- merged Q + KV projection GEMM (768 blocks) ----------------
// id<512: Qt (bf16 token-major). 512..639: Kt (bf16 token-major).
// 640..767: V written DIRECTLY TRANSPOSED into Vtr (B,16,64,1024) -- fuses v_transpose.
__global__ __launch_bounds__(256) void qkv_gemm_kernel(
    const __bf16* __restrict__ qn, const __bf16* __restrict__ kvn,
    const __bf16* __restrict__ wq, const __bf16* __restrict__ wkv,
    const float* __restrict__ qb, const float* __restrict__ kb, const float* __restrict__ vb,
    __bf16* __restrict__ Qt, __bf16* __restrict__ Kt, __bf16* __restrict__ Vtr) {
  __shared__ __attribute__((aligned(16))) char AsB[3 * 8192];
  __shared__ __attribute__((aligned(16))) char BsB[3 * 8192];
  int id = blockIdx.x;
  const __bf16 *A, *Bw; const float* bias; __bf16* Cout;
  int m0, n0, nloc;
  bool vmode = false;
  if (id < 512) {
    A = qn; Bw = wq; m0 = (id & 63) * 128; n0 = (id >> 6) * 128; nloc = n0;
    bias = qb; Cout = Qt;
  } else {
    int i2 = id - 512;
    A = kvn; Bw = wkv; m0 = (i2 & 15) * 128; n0 = (i2 >> 4) * 128;
    if (n0 < 1024) { bias = kb; Cout = Kt; nloc = n0; }
    else { bias = vb; Cout = Vtr; nloc = n0 - 1024; vmode = true; }
  }
  gemm_core(A, Bw, m0, n0, AsB, BsB,
            [&](f32x4 (&acc)[4][4], int lane, int wr, int wc) {
#pragma unroll
              for (int m = 0; m < 4; m++)
#pragma unroll
                for (int n = 0; n < 4; n++) {
                  int col = nloc + wc * 64 + n * 16 + (lane & 15);
                  float bv = bias[col];
                  if (!vmode) {
#pragma unroll
                    for (int r = 0; r < 4; r++) {
                      int row = m0 + wr * 64 + m * 16 + ((lane >> 4) << 2) + r;
                      Cout[((size_t)row << 10) + col] = (__bf16)(acc[m][n][r] + bv);
                    }
                  } else {
                    // transposed V store: 4 consecutive tokens at fixed (h,d) -> bf16x4
                    int row0 = m0 + wr * 64 + m * 16 + ((lane >> 4) << 2);
                    int bb = row0 >> 10, pos0 = row0 & 1023;
                    int hh = col >> 6, dd = col & 63;
                    bf16x4 v4;
#pragma unroll
                    for (int r = 0; r < 4; r++) v4[r] = (__bf16)(acc[m][n][r] + bv);
                    *(bf16x4*)(Cout + ((size_t)(((bb << 4) + hh) * 64 + dd) << 10) + pos0) = v4;
                  }
                }
            });
}

// ---------------- O-projection GEMM with residual epilogue (512 blocks) ----------------
__global__ __launch_bounds__(256) void gemm_o_kernel(
    const __bf16* __restrict__ A, const __bf16* __restrict__ Bw,
    const float* __restrict__ bias, float* __restrict__ Cout,
    const float* __restrict__ resid, const float* __restrict__ alphap) {
  __shared__ __attribute__((aligned(16))) char AsB[3 * 8192];
  __shared__ __attribute__((aligned(16))) char BsB[3 * 8192];
  int m0 = blockIdx.x * 128, n0 = blockIdx.y * 128;
  float aval = alphap[0];
  gemm_core(A, Bw, m0, n0, AsB, BsB,
            [&](f32x4 (&acc)[4][4], int lane, int wr, int wc) {
#pragma unroll
              for (int m = 0; m < 4; m++)
#pragma unroll
                for (int n = 0; n < 4; n++) {
                  int col = n0 + wc * 64 + n * 16 + (lane & 15);
                  float bv = bias[col];
#pragma unroll
                  for (int r = 0; r < 4; r++) {
                    int row = m0 + wr * 64 + m * 16 + ((lane >> 4) << 2) + r;
                    size_t idx = ((size_t)row << 10) + col;
                    Cout[idx] = resid[idx] + aval * (acc[m][n][r] + bv);
                  }
                }
            });
}

// ---------------- kprep: K head-RMSNorm+RoPE (V transpose now fused into qkv GEMM) --------
__global__ __launch_bounds__(256) void kprep_kernel(
    const __bf16* __restrict__ Kt, const float* __restrict__ KHW,
    const float* __restrict__ CCOS, const float* __restrict__ CSIN,
    __bf16* __restrict__ Kr) {
  int rb = blockIdx.x, tid = threadIdx.x;
  int inst = rb * 32 + (tid >> 3);
  int sub = tid & 7;
  int token = inst >> 4, h = inst & 15;
  int b = token >> 10, pos = token & 1023;
  const __bf16* xp = Kt + ((size_t)token << 10) + h * 64 + sub * 8;
  bf16x8 xv = *(const bf16x8*)xp;
  float xf[8];
#pragma unroll
  for (int i = 0; i < 8; i++) xf[i] = (float)xv[i];
  float ss = 0.f;
#pragma unroll
  for (int i = 0; i < 8; i++) ss += xf[i] * xf[i];
  ss += __shfl_xor(ss, 1);
  ss += __shfl_xor(ss, 2);
  ss += __shfl_xor(ss, 4);
  float rn = rsqrtf(ss * (1.0f / 64.0f) + 1e-6f);
  const float* hwp = KHW + sub * 8;
  const float* cp = CCOS + ((size_t)pos << 6) + sub * 8;
  const float* sp = CSIN + ((size_t)pos << 6) + sub * 8;
  float xn[8], o[8];
#pragma unroll
  for (int i = 0; i < 8; i++) xn[i] = xf[i] * rn * hwp[i];
#pragma unroll
  for (int i = 0; i < 8; i += 2) {
    o[i] = xn[i] * cp[i] - xn[i + 1] * sp[i];
    o[i + 1] = xn[i + 1] * cp[i + 1] + xn[i] * sp[i + 1];
  }
  bf16x8 yv;
#pragma unroll
  for (int i = 0; i < 8; i++) yv[i] = (__bf16)o[i];
  *(bf16x8*)(Kr + (((size_t)((b << 4) + h) << 10) + pos) * 64 + sub * 8) = yv;
}

// ---------------- flash attention (r13 structure: 256q/block, 64q/wave, 3-buffer) ---------
// Qt: (B*4096,1024) bf16 ; Kr: (B,16,1024,64) ; Vtr: (B,16,64,1024) ; AO: (B*4096,1024).
// 4 waves/block, each wave owns 64 q-rows (2 subtiles of 32; lane&31=q). Fragment-linear
// LDS (8 slots x 1KB per K/V tile): zero bank conflicts. 3 buffers, 2-tile-ahead staging,
// ONE raw s_barrier + s_waitcnt vmcnt(4) per tile (never a full drain in the loop).
// Softmax: bit-trick bf16 exp2 (bits = s*128 + MAGIC; rel err +-3% cancels in ratio) +
// ones-MFMA row-sum (denominator lane-local). XCD swizzle: 4 heads/XCD.
__global__ __launch_bounds__(256, 2) void attn_kernel(
    const __bf16* __restrict__ Qt, const float* __restrict__ QHW,
    const float* __restrict__ QCOS, const float* __restrict__ QSIN,
    const __bf16* __restrict__ Kr, const __bf16* __restrict__ Vtr,
    __bf16* __restrict__ AO) {
  int tid = threadIdx.x, lane = tid & 63, w = tid >> 6;
  int lq = lane & 31, hi = lane >> 5;
  // XCD swizzle (512 blocks, 8 XCDs, 64 blocks/XCD -> 4 heads per XCD)
  int wgid = blockIdx.x;
  int nid = (wgid & 7) * 64 + (wgid >> 3);
  int q0 = (nid & 15) * 256;
  int bh = nid >> 4, b = bh >> 4, h = bh & 15;
  const float QSC = 0.125f * 1.44269504088896340736f;  // 1/sqrt(64) * log2(e)
  const float MAGIC = 16250.5f;                        // (127 - 0.043) * 128, centered error

  __shared__ __attribute__((aligned(16))) __bf16 Ks[3][4096];
  __shared__ __attribute__((aligned(16))) __bf16 Vs[3][4096];

  const __bf16* Kbh = Kr + ((size_t)bh << 16);
  const __bf16* Vbh = Vtr + ((size_t)bh << 16);

  auto STAGE = [&](int T, int BSEL) {
#pragma unroll
    for (int i = 0; i < 2; i++) {
      int s = 2 * w + i;
      int kt = s >> 2, ds2 = s & 3;
      gload_lds16(Kbh + (size_t)(T * 64 + kt * 32 + lq) * 64 + ds2 * 16 + hi * 8,
                  (char*)Ks[BSEL] + s * 1024);
      int f = s >> 1, dh = s & 1;
      gload_lds16(Vbh + (size_t)(dh * 32 + lq) * 1024 + T * 64 + f * 16 + hi * 8,
                  (char*)Vs[BSEL] + s * 1024);
    }
  };

  STAGE(0, 0);
  STAGE(1, 1);

  // ---- fused Q head-RMSNorm + RoPE + scale for both q-subtiles (overlaps staging)
  bf16x8 qf[2][4];
#pragma unroll
  for (int qt = 0; qt < 2; qt++) {
    int pos = q0 + w * 64 + qt * 32 + lq;
    const __bf16* qp = Qt + ((size_t)(b * 4096 + pos) << 10) + h * 64 + hi * 8;
    float xf[4][8];
    float ss = 0.f;
#pragma unroll
    for (int ds = 0; ds < 4; ds++) {
      bf16x8 xv = *(const bf16x8*)(qp + ds * 16);
#pragma unroll
      for (int j = 0; j < 8; j++) { float f = (float)xv[j]; xf[ds][j] = f; ss += f * f; }
    }
    float2 sw = swap32(ss);
    float rn = rsqrtf((sw.x + sw.y) * (1.0f / 64.0f) + 1e-6f);
#pragma unroll
    for (int ds = 0; ds < 4; ds++) {
      int d0 = ds * 16 + hi * 8;
      const float* wp = QHW + d0;
      const float* cp = QCOS + ((size_t)pos << 6) + d0;
      const float* sp = QSIN + ((size_t)pos << 6) + d0;
      float4 wa = *(const float4*)wp, wb = *(const float4*)(wp + 4);
      float4 ca = *(const float4*)cp, cb = *(const float4*)(cp + 4);
      float4 sa = *(const float4*)sp, sb = *(const float4*)(sp + 4);
      float wv[8] = {wa.x, wa.y, wa.z, wa.w, wb.x, wb.y, wb.z, wb.w};
      float cv[8] = {ca.x, ca.y, ca.z, ca.w, cb.x, cb.y, cb.z, cb.w};
      float sv[8] = {sa.x, sa.y, sa.z, sa.w, sb.x, sb.y, sb.z, sb.w};
      float xn[8];
#pragma unroll
      for (int j = 0; j < 8; j++) xn[j] = xf[ds][j] * rn * wv[j];
      bf16x8 q8;
#pragma unroll
      for (int j = 0; j < 8; j += 2) {
        q8[j]     = (__bf16)((xn[j] * cv[j] - xn[j + 1] * sv[j]) * QSC);
        q8[j + 1] = (__bf16)((xn[j + 1] * cv[j + 1] + xn[j] * sv[j + 1]) * QSC);
      }
      qf[qt][ds] = q8;
    }
  }

  f32x16 Z16;
#pragma unroll
  for (int r = 0; r < 16; r++) Z16[r] = 0.f;
  f32x16 accO[2][2];
  f32x16 accR[2];  // row-sum accumulator (same C-layout rows as accO)
#pragma unroll
  for (int qt = 0; qt < 2; qt++) {
    accO[qt][0] = Z16; accO[qt][1] = Z16; accR[qt] = Z16;
  }
  bf16x8 ones8;
#pragma unroll
  for (int i = 0; i < 8; i++) ones8[i] = (__bf16)1.0f;

  // tile 0 resident (tile 1's loads may stay in flight)
  asm volatile("s_waitcnt vmcnt(4)" ::: "memory");
  __builtin_amdgcn_s_barrier();
  asm volatile("" ::: "memory");

  for (int t = 0; t < 16; t++) {
    int cur = t % 3;
    const char* kbase = (const char*)Ks[cur];
    const char* vbase = (const char*)Vs[cur];
    int loff = lane * 16;

    bf16x8 kf[8], vf[8];
#pragma unroll
    for (int s = 0; s < 8; s++) kf[s] = *(const bf16x8*)(kbase + s * 1024 + loff);
#pragma unroll
    for (int s = 0; s < 8; s++) vf[s] = *(const bf16x8*)(vbase + s * 1024 + loff);

    if (t + 2 < 16) STAGE(t + 2, (t + 2) % 3);

    f32x16 accS[2][2];
    __builtin_amdgcn_s_setprio(1);
#pragma unroll
    for (int qt = 0; qt < 2; qt++)
#pragma unroll
      for (int kt = 0; kt < 2; kt++) {
        accS[qt][kt] = __builtin_amdgcn_mfma_f32_32x32x16_bf16(kf[kt * 4], qf[qt][0], Z16, 0, 0, 0);
#pragma unroll
        for (int ds = 1; ds < 4; ds++)
          accS[qt][kt] = __builtin_amdgcn_mfma_f32_32x32x16_bf16(kf[kt * 4 + ds], qf[qt][ds], accS[qt][kt], 0, 0, 0);
      }
    __builtin_amdgcn_s_setprio(0);

    // P = approx exp2(S) as bf16 bits: bits16 = (u16)(s*128 + MAGIC)
    unsigned pa[2][4][4];
#pragma unroll
    for (int qt = 0; qt < 2; qt++)
#pragma unroll
      for (int kt = 0; kt < 2; kt++)
#pragma unroll
        for (int s2 = 0; s2 < 2; s2++) {
          int f = kt * 2 + s2, rb = s2 * 8;
          unsigned q[4];
#pragma unroll
          for (int i = 0; i < 4; i++) {
            float t0 = fmaf(accS[qt][kt][rb + 2 * i], 128.f, MAGIC);
            float t1 = fmaf(accS[qt][kt][rb + 2 * i + 1], 128.f, MAGIC);
            q[i] = ((unsigned)t1 << 16) | (unsigned)t0;
          }
          u32x2 r02 = __builtin_amdgcn_permlane32_swap(q[0], q[2], false, false);
          u32x2 r13 = __builtin_amdgcn_permlane32_swap(q[1], q[3], false, false);
          pa[qt][f][0] = r02.x; pa[qt][f][1] = r13.x; pa[qt][f][2] = r02.y; pa[qt][f][3] = r13.y;
        }

    __builtin_amdgcn_s_setprio(1);
#pragma unroll
    for (int f = 0; f < 4; f++)
#pragma unroll
      for (int qt = 0; qt < 2; qt++) {
        union { unsigned u[4]; bf16x8 v; } pf;
        pf.u[0] = pa[qt][f][0]; pf.u[1] = pa[qt][f][1];
        pf.u[2] = pa[qt][f][2]; pf.u[3] = pa[qt][f][3];
        accO[qt][0] = __builtin_amdgcn_mfma_f32_32x32x16_bf16(pf.v, vf[f * 2 + 0], accO[qt][0], 0, 0, 0);
        accO[qt][1] = __builtin_amdgcn_mfma_f32_32x32x16_bf16(pf.v, vf[f * 2 + 1], accO[qt][1], 0, 0, 0);
        accR[qt]    = __builtin_amdgcn_mfma_f32_32x32x16_bf16(pf.v, ones8, accR[qt], 0, 0, 0);
      }
    __builtin_amdgcn_s_setprio(0);

    // counted wait: tile t+1's loads complete; t+2's stay in flight
    if (t + 2 < 16) {
      asm volatile("s_waitcnt vmcnt(4)" ::: "memory");
    } else if (t + 1 < 16) {
      asm volatile("s_waitcnt vmcnt(0)" ::: "memory");
    }
    __builtin_amdgcn_s_barrier();
    asm volatile("" ::: "memory");
  }

  // epilogue: denominator lane-local (accR rows == accO rows); no cross-lane ops
  __bf16* aobase = AO + (((size_t)b * 4096) << 10) + h * 64;
#pragma unroll
  for (int qt = 0; qt < 2; qt++) {
#pragma unroll
    for (int r = 0; r < 16; r++) {
      float rv = fast_rcp(accR[qt][r]);
      int cr = (r & 3) + ((r >> 2) << 3) + (hi << 2);
      size_t rowoff = ((size_t)(q0 + w * 64 + qt * 32 + cr) << 10);
#pragma unroll
      for (int dh = 0; dh < 2; dh++)
        aobase[rowoff + dh * 32 + lq] = (__bf16)(accO[qt][dh][r] * rv);
    }
  }
}

extern "C" void kernel_launch(void* const* d_in, const int* in_sizes, int n_in,
                              void* d_out, int out_size, void* d_ws, size_t ws_size,
                              hipStream_t stream) {
  const float* img  = (const float*)d_in[0];
  const float* cnd  = (const float*)d_in[1];
  const float* qnw  = (const float*)d_in[2];
  const float* kvnw = (const float*)d_in[3];
  const float* qhw  = (const float*)d_in[4];
  const float* khw  = (const float*)d_in[5];
  const float* qw   = (const float*)d_in[6];
  const float* qb   = (const float*)d_in[7];
  const float* kw   = (const float*)d_in[8];
  const float* kb   = (const float*)d_in[9];
  const float* vw   = (const float*)d_in[10];
  const float* vb   = (const float*)d_in[11];
  const float* ow   = (const float*)d_in[12];
  const float* ob   = (const float*)d_in[13];
  const float* alpha= (const float*)d_in[14];
  const float* icos = (const float*)d_in[15];
  const float* isin = (const float*)d_in[16];
  const float* ccos = (const float*)d_in[17];
  const float* csin = (const float*)d_in[18];
  float* out = (float*)d_out;

  __bf16* p = (__bf16*)d_ws;
  __bf16* wqb = p; p += 1048576;
  __bf16* wkb = p; p += 1048576;   // wkb..wvb contiguous = (2048,1024) KV weight
  __bf16* wvb = p; p += 1048576;
  __bf16* wob = p; p += 1048576;
  __bf16* qn  = p; p += 8388608;   // (8192,1024); reused as AO after Q-GEMM consumes it
  __bf16* kvn = p; p += 2097152;
  __bf16* Qt  = p; p += 8388608;
  __bf16* Kt  = p; p += 2097152;
  __bf16* Kr  = p; p += 2097152;
  __bf16* Vtr = p; p += 2097152;
  __bf16* AO  = qn;  // qn dead after Q-GEMM

  prep_kernel<<<12288, 256, 0, stream>>>(img, qnw, qn, cnd, kvnw, kvn,
                                         qw, kw, vw, ow, wqb, wkb, wvb, wob);

  qkv_gemm_kernel<<<768, 256, 0, stream>>>(qn, kvn, wqb, wkb, qb, kb, vb, Qt, Kt, Vtr);

  kprep_kernel<<<1024, 256, 0, stream>>>(Kt, khw, ccos, csin, Kr);

  attn_kernel<<<512, 256, 0, stream>>>(Qt, qhw, icos, isin, Kr, Vtr, AO);

  gemm_o_kernel<<<dim3(64, 8), 256, 0, stream>>>(AO, wob, ob, out, img, alpha);
}